// Round 11
// baseline (313.733 us; speedup 1.0000x reference)
//
#include <hip/hip_runtime.h>
#include <math.h>

#define BB 64
#define TT 256
#define KK 32
#define VV 32
#define CH 32                    // output rows owned per block-tile
#define PH 32                    // steps per phase (= halo depth)
#define NPHASE 9                 // 9 * 32 = 288 steps
#define BPB 8                    // chunks per batch
#define NBP 32                   // batch pairs: tiles (bp, bp+32)
#define NW 4                     // waves per block
#define NTHR 256

// workspace layout (floats)
#define RW_OFF    0                       // K*K
#define WOP_OFF   1024                    // 37*K
#define ATOM_OFF  2240                    // B*T*K
#define STATE_OFF (ATOM_OFF + BB*TT*KK)   // B*T*K (phase-boundary handoff)
#define FLAG_OFF  (STATE_OFF + BB*TT*KK)  // NBP*BPB ints

typedef __attribute__((ext_vector_type(8))) short short8;
typedef __attribute__((ext_vector_type(4))) float floatx4;
typedef __attribute__((ext_vector_type(4))) int intx4;

__device__ __forceinline__ float myrelu(float z) {
    return fmaf(0.01f, z, 0.99f * __builtin_amdgcn_fmed3f(z, 0.f, 1.f));
}
__device__ __forceinline__ ushort f2bf(float f) {
    union { float f; unsigned int u; } v; v.f = f;
    unsigned int r = v.u + 0x7fffu + ((v.u >> 16) & 1u);
    return (ushort)(r >> 16);
}
__device__ __forceinline__ float dpp_shl1_f(float v) {
    // lane n <- lane n+1 within each 16-lane row; lane 15 of row -> 0
    return __int_as_float(__builtin_amdgcn_update_dpp(
        0, __float_as_int(v), 0x101, 0xF, 0xF, true));
}

// --- softmaxes of w_op (32 x 37) and w_right (32 x 33) ---
__global__ void prep_kernel(const float* __restrict__ w_right,
                            const float* __restrict__ w_op,
                            float* __restrict__ ws) {
    int tid = threadIdx.x;
    float* rw  = ws + RW_OFF;   // rw[k*K + j] = softmax(w_right)[j][k]
    float* wop = ws + WOP_OFF;  // wop[i*K + k] = sm_op[k][i]
    if (tid < KK) {
        float v[37];
        float m = -1e30f;
        #pragma unroll
        for (int i = 0; i < 37; ++i) { v[i] = w_op[tid * 37 + i]; m = fmaxf(m, v[i]); }
        float s = 0.f;
        #pragma unroll
        for (int i = 0; i < 37; ++i) { v[i] = expf(v[i] - m); s += v[i]; }
        float inv = 1.f / s;
        #pragma unroll
        for (int i = 0; i < 37; ++i) wop[i * KK + tid] = v[i] * inv;
    } else if (tid < 2 * KK) {
        int r = tid - KK;
        float v[KK + 1];
        float m = -1e30f;
        #pragma unroll
        for (int i = 0; i <= KK; ++i) { v[i] = w_right[r * (KK + 1) + i]; m = fmaxf(m, v[i]); }
        float s = 0.f;
        #pragma unroll
        for (int i = 0; i <= KK; ++i) { v[i] = expf(v[i] - m); s += v[i]; }
        float inv = 1.f / s;
        #pragma unroll
        for (int c = 0; c < KK; ++c) rw[c * KK + r] = v[c] * inv;
    }
}

// --- atom_x = x @ atom_w ; zero the handshake flags ---
__global__ void atomx_kernel(const float* __restrict__ x, float* __restrict__ ws) {
    const float* aw = ws + WOP_OFF + 5 * KK;
    float* atom = ws + ATOM_OFF;
    int tid = threadIdx.x;
    if (blockIdx.x == 0 && tid < NBP * BPB) ((int*)(ws + FLAG_OFF))[tid] = 0;
    int k  = tid & (KK - 1);
    int bt = blockIdx.x * 8 + (tid >> 5);
    const float* xrow = x + bt * VV;
    float acc = 0.f;
    #pragma unroll
    for (int v = 0; v < VV; ++v) acc = fmaf(xrow[v], aw[v * KK + k], acc);
    atom[bt * KK + k] = acc;
}

// --- all 288 steps; each wave runs TWO independent batch-tiles, r4-proven math ---
__global__ __launch_bounds__(NTHR, 1)
void phase_all_kernel(float* __restrict__ ws, float* __restrict__ out) {
    __shared__ float brow[2][2][NW + 1][36];   // [tile][buf][strip][36]

    const float* rw   = ws + RW_OFF;
    const float* wop  = ws + WOP_OFF;
    const float* atom = ws + ATOM_OFF;
    float*      state = ws + STATE_OFF;
    int*        flags = (int*)(ws + FLAG_OFF);

    int tid  = threadIdx.x;
    int lane = tid & 63;
    int rt   = tid >> 6;          // wave = row-group 0..3
    int lr   = lane & 15;
    int hi   = lane >> 4;
    int bp = blockIdx.x >> 3;     // batch pair 0..31
    int c  = blockIdx.x & 7;      // chunk 0..7
    int lo = c * CH;
    int bA = bp, bB = bp + NBP;
    int t0 = lo + rt * 16 + lr;   // this lane's global row (both tiles)
    bool active = (lo + rt * 16) < TT;   // wave-uniform

    for (int i = tid; i < 2 * 2 * (NW + 1) * 36; i += NTHR)
        (&brow[0][0][0][0])[i] = 0.f;

    float* gsA = state + (size_t)bA * TT * KK;
    float* gsB = state + (size_t)bB * TT * KK;

    float Ay[8], By[8];
    #pragma unroll
    for (int q = 0; q < 8; ++q) { Ay[q] = 0.f; By[q] = 0.f; }

    // shared per-lane weights (cols hi*8..hi*8+7) + per-tile C operands
    // r4-proven decomposition: z = le*d1p + nx*w4n + t*w4c + xl*w3 + acc,
    // acc = MFMA(rw*(w2+w4), y) + c0;  c0 = av + w1 - w2 - w4
    float d1p[8], w4n[8], w4c[8], w3v[8];
    floatx4 c0Aa, c0Ab, c0Ba, c0Bb;
    {
        const float* w1p = wop + 1 * KK + hi * 8;
        const float* w2p = wop + 2 * KK + hi * 8;
        const float* w3p = wop + 3 * KK + hi * 8;
        const float* w4p = wop + 4 * KK + hi * 8;
        float avA[8], avB[8];
        #pragma unroll
        for (int q = 0; q < 8; ++q) { avA[q] = 0.f; avB[q] = 0.f; }
        if (t0 < TT) {
            float4 a0 = *reinterpret_cast<const float4*>(&atom[((size_t)bA * TT + t0) * KK + hi * 8]);
            float4 a1 = *reinterpret_cast<const float4*>(&atom[((size_t)bA * TT + t0) * KK + hi * 8 + 4]);
            float4 b0 = *reinterpret_cast<const float4*>(&atom[((size_t)bB * TT + t0) * KK + hi * 8]);
            float4 b1 = *reinterpret_cast<const float4*>(&atom[((size_t)bB * TT + t0) * KK + hi * 8 + 4]);
            avA[0] = a0.x; avA[1] = a0.y; avA[2] = a0.z; avA[3] = a0.w;
            avA[4] = a1.x; avA[5] = a1.y; avA[6] = a1.z; avA[7] = a1.w;
            avB[0] = b0.x; avB[1] = b0.y; avB[2] = b0.z; avB[3] = b0.w;
            avB[4] = b1.x; avB[5] = b1.y; avB[6] = b1.z; avB[7] = b1.w;
        }
        float base[8];
        #pragma unroll
        for (int q = 0; q < 8; ++q) {
            base[q] = w1p[q] - w2p[q] - w4p[q];
            d1p[q]  = (w2p[q] - w1p[q]) + 0.01f * w4p[q];
            w4n[q]  = 0.01f * w4p[q];
            w4c[q]  = 0.99f * w4p[q];
            w3v[q]  = w3p[q];
        }
        c0Aa = (floatx4){avA[0]+base[0], avA[1]+base[1], avA[2]+base[2], avA[3]+base[3]};
        c0Ab = (floatx4){avA[4]+base[4], avA[5]+base[5], avA[6]+base[6], avA[7]+base[7]};
        c0Ba = (floatx4){avB[0]+base[0], avB[1]+base[1], avB[2]+base[2], avB[3]+base[3]};
        c0Bb = (floatx4){avB[4]+base[4], avB[5]+base[5], avB[6]+base[6], avB[7]+base[7]};
    }

    // A fragments: scale-only fold (r4-proven): A[k][col] = rw[k][col]*(w2+w4)[col]
    short8 af0, af1;
    {
        int col0 = ((lr >> 2) << 3) | (lr & 3);
        int col1 = col0 + 4;
        float sa = wop[2 * KK + col0] + wop[4 * KK + col0];
        float sb = wop[2 * KK + col1] + wop[4 * KK + col1];
        int k0 = hi * 8;
        #pragma unroll
        for (int q = 0; q < 8; ++q) {
            af0[q] = (short)f2bf(rw[(k0 + q) * KK + col0] * sa);
            af1[q] = (short)f2bf(rw[(k0 + q) * KK + col1] * sb);
        }
    }

    bool h3 = (hi == 3);
    int pidx = ((lane + 16) & 63) << 2;   // bpermute addr for lane+16
    __syncthreads();

    for (int p = 0; p < NPHASE; ++p) {
        for (int s = 0; s < PH; ++s) {
            int cur = s & 1;
            if (active) {
                // --- chain heads: both tiles' neighbor rows (independent) ---
                float Anx[8], Bnx[8];
                #pragma unroll
                for (int q = 0; q < 8; ++q) { Anx[q] = dpp_shl1_f(Ay[q]); Bnx[q] = dpp_shl1_f(By[q]); }
                float AlbR = __int_as_float(__builtin_amdgcn_ds_bpermute(pidx, __float_as_int(Ay[0])));
                float BlbR = __int_as_float(__builtin_amdgcn_ds_bpermute(pidx, __float_as_int(By[0])));
                float Alb = h3 ? 0.f : AlbR;
                float Blb = h3 ? 0.f : BlbR;
                float Axb = dpp_shl1_f(Alb);  if (h3) Axb = 0.f;
                float Bxb = dpp_shl1_f(Blb);  if (h3) Bxb = 0.f;
                if (lr == 15) {     // r4-proven branch: boundary row from strip
                    const float* brA = &brow[0][cur][rt + 1][hi * 8];
                    float4 a0 = *reinterpret_cast<const float4*>(brA);
                    float4 a1 = *reinterpret_cast<const float4*>(brA + 4);
                    Anx[0] = a0.x; Anx[1] = a0.y; Anx[2] = a0.z; Anx[3] = a0.w;
                    Anx[4] = a1.x; Anx[5] = a1.y; Anx[6] = a1.z; Anx[7] = a1.w;
                    Axb = brA[8];   // pad col 32 == 0 for hi==3
                    const float* brB = &brow[1][cur][rt + 1][hi * 8];
                    float4 b0 = *reinterpret_cast<const float4*>(brB);
                    float4 b1 = *reinterpret_cast<const float4*>(brB + 4);
                    Bnx[0] = b0.x; Bnx[1] = b0.y; Bnx[2] = b0.z; Bnx[3] = b0.w;
                    Bnx[4] = b1.x; Bnx[5] = b1.y; Bnx[6] = b1.z; Bnx[7] = b1.w;
                    Bxb = brB[8];
                }

                // --- fragments + MFMAs (A then B; B's issue hides A's latency) ---
                unsigned aw0, aw1, aw2, aw3, bw0, bw1, bw2, bw3;
                asm("v_cvt_pk_bf16_f32 %0, %1, %2" : "=v"(aw0) : "v"(Ay[0]), "v"(Ay[1]));
                asm("v_cvt_pk_bf16_f32 %0, %1, %2" : "=v"(aw1) : "v"(Ay[2]), "v"(Ay[3]));
                asm("v_cvt_pk_bf16_f32 %0, %1, %2" : "=v"(aw2) : "v"(Ay[4]), "v"(Ay[5]));
                asm("v_cvt_pk_bf16_f32 %0, %1, %2" : "=v"(aw3) : "v"(Ay[6]), "v"(Ay[7]));
                short8 bvA = __builtin_bit_cast(short8,
                    (intx4){(int)aw0, (int)aw1, (int)aw2, (int)aw3});
                floatx4 aA0 = __builtin_amdgcn_mfma_f32_16x16x32_bf16(af0, bvA, c0Aa, 0, 0, 0);
                floatx4 aA1 = __builtin_amdgcn_mfma_f32_16x16x32_bf16(af1, bvA, c0Ab, 0, 0, 0);
                asm("v_cvt_pk_bf16_f32 %0, %1, %2" : "=v"(bw0) : "v"(By[0]), "v"(By[1]));
                asm("v_cvt_pk_bf16_f32 %0, %1, %2" : "=v"(bw1) : "v"(By[2]), "v"(By[3]));
                asm("v_cvt_pk_bf16_f32 %0, %1, %2" : "=v"(bw2) : "v"(By[4]), "v"(By[5]));
                asm("v_cvt_pk_bf16_f32 %0, %1, %2" : "=v"(bw3) : "v"(By[6]), "v"(By[7]));
                short8 bvB = __builtin_bit_cast(short8,
                    (intx4){(int)bw0, (int)bw1, (int)bw2, (int)bw3});
                floatx4 aB0 = __builtin_amdgcn_mfma_f32_16x16x32_bf16(af0, bvB, c0Ba, 0, 0, 0);
                floatx4 aB1 = __builtin_amdgcn_mfma_f32_16x16x32_bf16(af1, bvB, c0Bb, 0, 0, 0);

                // --- tails (r4-verbatim), A then B ---
                #pragma unroll
                for (int q = 0; q < 8; ++q) {
                    float accq = (q < 4) ? aA0[q] : aA1[q - 4];
                    float le = (q < 7) ? Ay[q + 1] : Alb;
                    float xl = (q < 7) ? Anx[q + 1] : Axb;
                    float sm = le + Anx[q];
                    float t  = __builtin_amdgcn_fmed3f(sm, 1.f, 2.f);
                    float z  = fmaf(le, d1p[q],
                               fmaf(Anx[q], w4n[q],
                               fmaf(t, w4c[q],
                               fmaf(xl, w3v[q], accq))));
                    Ay[q] = myrelu(z);
                }
                #pragma unroll
                for (int q = 0; q < 8; ++q) {
                    float accq = (q < 4) ? aB0[q] : aB1[q - 4];
                    float le = (q < 7) ? By[q + 1] : Blb;
                    float xl = (q < 7) ? Bnx[q + 1] : Bxb;
                    float sm = le + Bnx[q];
                    float t  = __builtin_amdgcn_fmed3f(sm, 1.f, 2.f);
                    float z  = fmaf(le, d1p[q],
                               fmaf(Bnx[q], w4n[q],
                               fmaf(t, w4c[q],
                               fmaf(xl, w3v[q], accq))));
                    By[q] = myrelu(z);
                }

                if (lr == 0) {
                    float* wA = &brow[0][cur ^ 1][rt][hi * 8];
                    *reinterpret_cast<float4*>(wA)     = make_float4(Ay[0], Ay[1], Ay[2], Ay[3]);
                    *reinterpret_cast<float4*>(wA + 4) = make_float4(Ay[4], Ay[5], Ay[6], Ay[7]);
                    float* wB = &brow[1][cur ^ 1][rt][hi * 8];
                    *reinterpret_cast<float4*>(wB)     = make_float4(By[0], By[1], By[2], By[3]);
                    *reinterpret_cast<float4*>(wB + 4) = make_float4(By[4], By[5], By[6], By[7]);
                }
            }
            __syncthreads();
        }
        if (p == NPHASE - 1) break;

        // ---- phase boundary: publish owned rows (both tiles) + release flag ----
        if (rt < 2 && c > 0) {
            float* gA = gsA + (size_t)t0 * KK + hi * 8;
            *reinterpret_cast<float4*>(gA)     = make_float4(Ay[0], Ay[1], Ay[2], Ay[3]);
            *reinterpret_cast<float4*>(gA + 4) = make_float4(Ay[4], Ay[5], Ay[6], Ay[7]);
            float* gB = gsB + (size_t)t0 * KK + hi * 8;
            *reinterpret_cast<float4*>(gB)     = make_float4(By[0], By[1], By[2], By[3]);
            *reinterpret_cast<float4*>(gB + 4) = make_float4(By[4], By[5], By[6], By[7]);
        }
        __syncthreads();
        if (tid == 0) {
            if (c > 0)
                __hip_atomic_store(&flags[bp * BPB + c], p + 1,
                                   __ATOMIC_RELEASE, __HIP_MEMORY_SCOPE_AGENT);
            if (c < BPB - 1) {
                while (__hip_atomic_load(&flags[bp * BPB + c + 1],
                                         __ATOMIC_ACQUIRE, __HIP_MEMORY_SCOPE_AGENT) < p + 1)
                    __builtin_amdgcn_s_sleep(2);
            }
        }
        __syncthreads();
        if (active && rt >= 2) {           // halo waves reload fresh rows, both tiles
            unsigned long long* gA = reinterpret_cast<unsigned long long*>(gsA + (size_t)t0 * KK + hi * 8);
            unsigned long long* gB = reinterpret_cast<unsigned long long*>(gsB + (size_t)t0 * KK + hi * 8);
            unsigned long long a0 = __hip_atomic_load(&gA[0], __ATOMIC_RELAXED, __HIP_MEMORY_SCOPE_AGENT);
            unsigned long long a1 = __hip_atomic_load(&gA[1], __ATOMIC_RELAXED, __HIP_MEMORY_SCOPE_AGENT);
            unsigned long long a2 = __hip_atomic_load(&gA[2], __ATOMIC_RELAXED, __HIP_MEMORY_SCOPE_AGENT);
            unsigned long long a3 = __hip_atomic_load(&gA[3], __ATOMIC_RELAXED, __HIP_MEMORY_SCOPE_AGENT);
            unsigned long long b0 = __hip_atomic_load(&gB[0], __ATOMIC_RELAXED, __HIP_MEMORY_SCOPE_AGENT);
            unsigned long long b1 = __hip_atomic_load(&gB[1], __ATOMIC_RELAXED, __HIP_MEMORY_SCOPE_AGENT);
            unsigned long long b2 = __hip_atomic_load(&gB[2], __ATOMIC_RELAXED, __HIP_MEMORY_SCOPE_AGENT);
            unsigned long long b3 = __hip_atomic_load(&gB[3], __ATOMIC_RELAXED, __HIP_MEMORY_SCOPE_AGENT);
            Ay[0] = __uint_as_float((unsigned)a0); Ay[1] = __uint_as_float((unsigned)(a0 >> 32));
            Ay[2] = __uint_as_float((unsigned)a1); Ay[3] = __uint_as_float((unsigned)(a1 >> 32));
            Ay[4] = __uint_as_float((unsigned)a2); Ay[5] = __uint_as_float((unsigned)(a2 >> 32));
            Ay[6] = __uint_as_float((unsigned)a3); Ay[7] = __uint_as_float((unsigned)(a3 >> 32));
            By[0] = __uint_as_float((unsigned)b0); By[1] = __uint_as_float((unsigned)(b0 >> 32));
            By[2] = __uint_as_float((unsigned)b1); By[3] = __uint_as_float((unsigned)(b1 >> 32));
            By[4] = __uint_as_float((unsigned)b2); By[5] = __uint_as_float((unsigned)(b2 >> 32));
            By[6] = __uint_as_float((unsigned)b3); By[7] = __uint_as_float((unsigned)(b3 >> 32));
            if (lr == 0) {                 // refresh boundary strips for next phase
                float* wA = &brow[0][0][rt][hi * 8];
                *reinterpret_cast<float4*>(wA)     = make_float4(Ay[0], Ay[1], Ay[2], Ay[3]);
                *reinterpret_cast<float4*>(wA + 4) = make_float4(Ay[4], Ay[5], Ay[6], Ay[7]);
                float* wB = &brow[1][0][rt][hi * 8];
                *reinterpret_cast<float4*>(wB)     = make_float4(By[0], By[1], By[2], By[3]);
                *reinterpret_cast<float4*>(wB + 4) = make_float4(By[4], By[5], By[6], By[7]);
            }
        }
        __syncthreads();
    }

    // epilogue: sigmoid + store owned rows (waves 0,1), both tiles
    if (rt < 2) {
        float* oA = out + ((size_t)bA * TT + t0) * KK + hi * 8;
        float* oB = out + ((size_t)bB * TT + t0) * KK + hi * 8;
        float oa[8], ob[8];
        #pragma unroll
        for (int q = 0; q < 8; ++q) {
            oa[q] = 1.f / (1.f + __expf(-5.f * (Ay[q] - 0.5f)));
            ob[q] = 1.f / (1.f + __expf(-5.f * (By[q] - 0.5f)));
        }
        *reinterpret_cast<float4*>(&oA[0]) = make_float4(oa[0], oa[1], oa[2], oa[3]);
        *reinterpret_cast<float4*>(&oA[4]) = make_float4(oa[4], oa[5], oa[6], oa[7]);
        *reinterpret_cast<float4*>(&oB[0]) = make_float4(ob[0], ob[1], ob[2], ob[3]);
        *reinterpret_cast<float4*>(&oB[4]) = make_float4(ob[4], ob[5], ob[6], ob[7]);
    }
}

extern "C" void kernel_launch(void* const* d_in, const int* in_sizes, int n_in,
                              void* d_out, int out_size, void* d_ws, size_t ws_size,
                              hipStream_t stream) {
    const float* x       = (const float*)d_in[0];
    const float* w_right = (const float*)d_in[1];
    const float* w_op    = (const float*)d_in[2];
    float* ws  = (float*)d_ws;
    float* out = (float*)d_out;

    prep_kernel<<<1, 64, 0, stream>>>(w_right, w_op, ws);
    atomx_kernel<<<BB * TT / 8, 256, 0, stream>>>(x, ws);

    void* args[] = { (void*)&ws, (void*)&out };
    hipLaunchCooperativeKernel((void*)phase_all_kernel,
                               dim3(NBP * BPB), dim3(NTHR), args, 0, stream);
}

// Round 12
// 229.102 us; speedup vs baseline: 1.3694x; 1.3694x over previous
//
#include <hip/hip_runtime.h>
#include <math.h>

#define BB 64
#define TT 256
#define KK 32
#define VV 32
#define CH 64                    // output rows owned per block
#define PH 32                    // steps per phase
#define ROWS (CH + PH)           // 96 rows covered per block
#define NPHASE ((TT + KK) / PH)  // 9 phases * 32 = 288 steps
#define BPB (TT / CH)            // 4 chunks per batch
#define NW (ROWS / 16)           // 6 waves per block
#define NTHR (NW * 64)           // 384 threads

// workspace layout (floats)
#define RW_OFF    0                       // K*K
#define WOP_OFF   1024                    // 37*K
#define AWT_OFF   2240                    // K*K transposed atom weights awT[k][v]
#define STATE_OFF (AWT_OFF + KK*KK)       // B*T*K (phase-boundary handoff)
#define FLAG_OFF  (STATE_OFF + BB*TT*KK)  // BB*BPB ints

typedef __attribute__((ext_vector_type(8))) short short8;
typedef __attribute__((ext_vector_type(4))) float floatx4;
typedef __attribute__((ext_vector_type(4))) int intx4;

__device__ __forceinline__ float myrelu(float z) {
    // 0.01*z + 0.99*clamp(z,0,1)
    return fmaf(0.01f, z, 0.99f * __builtin_amdgcn_fmed3f(z, 0.f, 1.f));
}
__device__ __forceinline__ ushort f2bf(float f) {
    union { float f; unsigned int u; } v; v.f = f;
    unsigned int r = v.u + 0x7fffu + ((v.u >> 16) & 1u);
    return (ushort)(r >> 16);
}
__device__ __forceinline__ float dpp_shl1(float v) {
    // lane n <- lane n+1 within each 16-lane row; top lane of row -> 0
    return __int_as_float(__builtin_amdgcn_update_dpp(
        0, __float_as_int(v), 0x101 /*row_shl:1*/, 0xF, 0xF, true));
}

// --- softmaxes of w_op (32 x 37) and w_right (32 x 33); awT; zero flags ---
__global__ void prep_kernel(const float* __restrict__ w_right,
                            const float* __restrict__ w_op,
                            float* __restrict__ ws) {
    int tid = threadIdx.x;
    float* rw  = ws + RW_OFF;   // rw[k*K + j] = right_w[k][j] = softmax(w_right)[j][k]
    float* wop = ws + WOP_OFF;  // wop[i*K + k] = sm_op[k][i]
    float* awt = ws + AWT_OFF;  // awt[k*K + v] = sm_op[k][5+v]  (transposed atom weights)
    int*   flags = (int*)(ws + FLAG_OFF);
    for (int i = tid; i < BB * BPB; i += 64) flags[i] = 0;
    if (tid < KK) {
        float v[37];
        float m = -1e30f;
        #pragma unroll
        for (int i = 0; i < 37; ++i) { v[i] = w_op[tid * 37 + i]; m = fmaxf(m, v[i]); }
        float s = 0.f;
        #pragma unroll
        for (int i = 0; i < 37; ++i) { v[i] = expf(v[i] - m); s += v[i]; }
        float inv = 1.f / s;
        #pragma unroll
        for (int i = 0; i < 37; ++i) wop[i * KK + tid] = v[i] * inv;
        #pragma unroll
        for (int i = 0; i < KK; ++i) awt[tid * KK + i] = v[5 + i] * inv;
    } else if (tid < 2 * KK) {
        int r = tid - KK;
        float v[KK + 1];
        float m = -1e30f;
        #pragma unroll
        for (int i = 0; i <= KK; ++i) { v[i] = w_right[r * (KK + 1) + i]; m = fmaxf(m, v[i]); }
        float s = 0.f;
        #pragma unroll
        for (int i = 0; i <= KK; ++i) { v[i] = expf(v[i] - m); s += v[i]; }
        float inv = 1.f / s;
        #pragma unroll
        for (int c = 0; c < KK; ++c) rw[c * KK + r] = v[c] * inv;
    }
}

// --- all 288 steps; r4-verbatim step body; lean handshake; fused atom prologue ---
__global__ __launch_bounds__(NTHR, 1)
void phase_all_kernel(const float* __restrict__ x,
                      float* __restrict__ ws, float* __restrict__ out) {
    __shared__ float brow[2][NW + 1][36];   // tile-boundary rows, dbuf

    const float* rw   = ws + RW_OFF;
    const float* wop  = ws + WOP_OFF;
    const float* awt  = ws + AWT_OFF;
    float*      state = ws + STATE_OFF;
    int*        flags = (int*)(ws + FLAG_OFF);

    int tid  = threadIdx.x;
    int lane = tid & 63;
    int rt   = tid >> 6;        // wave = row-tile 0..5
    int lr   = lane & 15;
    int hi   = lane >> 4;
    int b  = blockIdx.x / BPB;
    int c  = blockIdx.x % BPB;
    int lo = c * CH;
    int t0 = lo + rt * 16 + lr;            // this lane's global row
    bool active = (lo + rt * 16) < TT;     // wave-uniform

    for (int i = tid; i < 2 * (NW + 1) * 36; i += NTHR)
        (&brow[0][0][0])[i] = 0.f;

    float* gs = state + (size_t)b * TT * KK;

    float y[8];
    #pragma unroll
    for (int q = 0; q < 8; ++q) y[q] = 0.f;

    // fused atom: av[q] = dot(x[b,t0,:], awT[hi*8+q][:])
    float av[8];
    #pragma unroll
    for (int q = 0; q < 8; ++q) av[q] = 0.f;
    if (t0 < TT) {
        const float* xr = x + ((size_t)b * TT + t0) * VV;
        float xv[32];
        #pragma unroll
        for (int i = 0; i < 8; ++i) {
            float4 v = *reinterpret_cast<const float4*>(xr + 4 * i);
            xv[4 * i + 0] = v.x; xv[4 * i + 1] = v.y;
            xv[4 * i + 2] = v.z; xv[4 * i + 3] = v.w;
        }
        #pragma unroll
        for (int q = 0; q < 8; ++q) {
            const float* ar = awt + (hi * 8 + q) * KK;
            float acc = 0.f;
            #pragma unroll
            for (int i = 0; i < 8; ++i) {
                float4 a = *reinterpret_cast<const float4*>(ar + 4 * i);
                acc = fmaf(xv[4 * i + 0], a.x, acc);
                acc = fmaf(xv[4 * i + 1], a.y, acc);
                acc = fmaf(xv[4 * i + 2], a.z, acc);
                acc = fmaf(xv[4 * i + 3], a.w, acc);
            }
            av[q] = acc;
        }
    }

    // per-lane constants for cols hi*8..hi*8+7 (r4 decomposition):
    // z = le*d1p + nx*w4n + med3(le+nx,1,2)*w4c + xl*w3 + acc ; acc = MFMA + c0p
    float c0p[8], d1p[8], w3v[8], w4n[8], w4c[8];
    {
        #pragma unroll
        for (int q = 0; q < 8; ++q) {
            int j = hi * 8 + q;
            float w1 = wop[1 * KK + j];
            float w2 = wop[2 * KK + j];
            float w3 = wop[3 * KK + j];
            float w4 = wop[4 * KK + j];
            c0p[q] = av[q] + w1 - w2 - w4;
            d1p[q] = (w2 - w1) + 0.01f * w4;
            w4n[q] = 0.01f * w4;
            w4c[q] = 0.99f * w4;
            w3v[q] = w3;
        }
    }

    // A fragments scaled by (w2+w4) per output column; col0(m)=(m>>2)*8+(m&3)
    short8 af0, af1;
    {
        int col0 = ((lr >> 2) << 3) | (lr & 3);
        float s0 = wop[2 * KK + col0]     + wop[4 * KK + col0];
        float s1 = wop[2 * KK + col0 + 4] + wop[4 * KK + col0 + 4];
        #pragma unroll
        for (int q = 0; q < 8; ++q) {
            af0[q] = (short)f2bf(rw[(hi * 8 + q) * KK + col0] * s0);
            af1[q] = (short)f2bf(rw[(hi * 8 + q) * KK + col0 + 4] * s1);
        }
    }

    int pidx = ((lane + 16) & 63) << 2;   // bpermute byte addr for lane+16
    __syncthreads();

    for (int p = 0; p < NPHASE; ++p) {
        for (int s = 0; s < PH; ++s) {
            int cur = s & 1;
            if (active) {
                unsigned bw0, bw1, bw2, bw3;
                asm("v_cvt_pk_bf16_f32 %0, %1, %2" : "=v"(bw0) : "v"(y[0]), "v"(y[1]));
                asm("v_cvt_pk_bf16_f32 %0, %1, %2" : "=v"(bw1) : "v"(y[2]), "v"(y[3]));
                asm("v_cvt_pk_bf16_f32 %0, %1, %2" : "=v"(bw2) : "v"(y[4]), "v"(y[5]));
                asm("v_cvt_pk_bf16_f32 %0, %1, %2" : "=v"(bw3) : "v"(y[6]), "v"(y[7]));
                short8 bv = __builtin_bit_cast(short8,
                    (intx4){(int)bw0, (int)bw1, (int)bw2, (int)bw3});
                floatx4 acc0 = __builtin_amdgcn_mfma_f32_16x16x32_bf16(
                    af0, bv, (floatx4){c0p[0], c0p[1], c0p[2], c0p[3]}, 0, 0, 0);
                floatx4 acc1 = __builtin_amdgcn_mfma_f32_16x16x32_bf16(
                    af1, bv, (floatx4){c0p[4], c0p[5], c0p[6], c0p[7]}, 0, 0, 0);

                // neighbor row r+1 via DPP; 16-row tile boundary via LDS strip
                float nx[8];
                #pragma unroll
                for (int q = 0; q < 8; ++q) nx[q] = dpp_shl1(y[q]);
                float lbr = __int_as_float(__builtin_amdgcn_ds_bpermute(pidx, __float_as_int(y[0])));
                float lb  = (hi == 3) ? 0.f : lbr;    // row r, col hi*8+8
                float xb  = dpp_shl1(lb);             // row r+1, col hi*8+8
                if (hi == 3) xb = 0.f;
                if (lr == 15) {
                    float4 n0 = *reinterpret_cast<const float4*>(&brow[cur][rt + 1][hi * 8]);
                    float4 n1 = *reinterpret_cast<const float4*>(&brow[cur][rt + 1][hi * 8 + 4]);
                    nx[0] = n0.x; nx[1] = n0.y; nx[2] = n0.z; nx[3] = n0.w;
                    nx[4] = n1.x; nx[5] = n1.y; nx[6] = n1.z; nx[7] = n1.w;
                    xb = brow[cur][rt + 1][hi * 8 + 8];   // pad col 32 == 0 for hi==3
                }

                float le[8], xl[8];
                #pragma unroll
                for (int q = 0; q < 7; ++q) { le[q] = y[q + 1]; xl[q] = nx[q + 1]; }
                le[7] = lb; xl[7] = xb;

                #pragma unroll
                for (int q = 0; q < 8; ++q) {
                    float accq = (q < 4) ? acc0[q] : acc1[q - 4];
                    float sm = le[q] + nx[q];
                    float t  = __builtin_amdgcn_fmed3f(sm, 1.f, 2.f);
                    float z  = fmaf(le[q], d1p[q],
                               fmaf(nx[q], w4n[q],
                               fmaf(t, w4c[q],
                               fmaf(xl[q], w3v[q], accq))));
                    y[q] = myrelu(z);
                }
                if (lr == 0) {
                    *reinterpret_cast<float4*>(&brow[cur ^ 1][rt][hi * 8])     = make_float4(y[0], y[1], y[2], y[3]);
                    *reinterpret_cast<float4*>(&brow[cur ^ 1][rt][hi * 8 + 4]) = make_float4(y[4], y[5], y[6], y[7]);
                }
            }
            __syncthreads();
        }
        if (p == NPHASE - 1) break;

        // ---- phase boundary: plain coalesced publish + release flag (lean, r8-proven) ----
        if (rt < 2 && c > 0) {     // publish owned rows 0..31
            float* gp = gs + (size_t)t0 * KK + hi * 8;
            *reinterpret_cast<float4*>(gp)     = make_float4(y[0], y[1], y[2], y[3]);
            *reinterpret_cast<float4*>(gp + 4) = make_float4(y[4], y[5], y[6], y[7]);
        }
        __syncthreads();   // vmcnt drained per-wave before barrier
        if (tid == 0) {
            if (c > 0)
                __hip_atomic_store(&flags[b * BPB + c], p + 1,
                                   __ATOMIC_RELEASE, __HIP_MEMORY_SCOPE_AGENT);
            if (c < BPB - 1) {
                while (__hip_atomic_load(&flags[b * BPB + c + 1],
                                         __ATOMIC_ACQUIRE, __HIP_MEMORY_SCOPE_AGENT) < p + 1)
                    __builtin_amdgcn_s_sleep(2);
            }
        }
        __syncthreads();
        if (active && rt >= CH / 16) {      // halo waves 4,5 reload fresh rows
            unsigned long long* gp =
                reinterpret_cast<unsigned long long*>(gs + (size_t)t0 * KK + hi * 8);
            unsigned long long u0 = __hip_atomic_load(&gp[0], __ATOMIC_RELAXED, __HIP_MEMORY_SCOPE_AGENT);
            unsigned long long u1 = __hip_atomic_load(&gp[1], __ATOMIC_RELAXED, __HIP_MEMORY_SCOPE_AGENT);
            unsigned long long u2 = __hip_atomic_load(&gp[2], __ATOMIC_RELAXED, __HIP_MEMORY_SCOPE_AGENT);
            unsigned long long u3 = __hip_atomic_load(&gp[3], __ATOMIC_RELAXED, __HIP_MEMORY_SCOPE_AGENT);
            y[0] = __uint_as_float((unsigned)u0); y[1] = __uint_as_float((unsigned)(u0 >> 32));
            y[2] = __uint_as_float((unsigned)u1); y[3] = __uint_as_float((unsigned)(u1 >> 32));
            y[4] = __uint_as_float((unsigned)u2); y[5] = __uint_as_float((unsigned)(u2 >> 32));
            y[6] = __uint_as_float((unsigned)u3); y[7] = __uint_as_float((unsigned)(u3 >> 32));
            if (lr == 0) {    // refresh boundary strip for next phase (reads brow[0])
                float* wp = &brow[0][rt][hi * 8];
                *reinterpret_cast<float4*>(wp)     = make_float4(y[0], y[1], y[2], y[3]);
                *reinterpret_cast<float4*>(wp + 4) = make_float4(y[4], y[5], y[6], y[7]);
            }
        }
        __syncthreads();
    }

    // epilogue: sigmoid + store owned rows (waves 0..3)
    if (rt < CH / 16) {
        float* op = out + ((size_t)b * TT + t0) * KK + hi * 8;
        float o[8];
        #pragma unroll
        for (int q = 0; q < 8; ++q)
            o[q] = 1.f / (1.f + __expf(-5.f * (y[q] - 0.5f)));
        *reinterpret_cast<float4*>(&op[0]) = make_float4(o[0], o[1], o[2], o[3]);
        *reinterpret_cast<float4*>(&op[4]) = make_float4(o[4], o[5], o[6], o[7]);
    }
}

extern "C" void kernel_launch(void* const* d_in, const int* in_sizes, int n_in,
                              void* d_out, int out_size, void* d_ws, size_t ws_size,
                              hipStream_t stream) {
    const float* x       = (const float*)d_in[0];
    const float* w_right = (const float*)d_in[1];
    const float* w_op    = (const float*)d_in[2];
    float* ws  = (float*)d_ws;
    float* out = (float*)d_out;

    prep_kernel<<<1, 64, 0, stream>>>(w_right, w_op, ws);

    void* args[] = { (void*)&x, (void*)&ws, (void*)&out };
    hipLaunchCooperativeKernel((void*)phase_all_kernel,
                               dim3(BB * BPB), dim3(NTHR), args, 0, stream);
}